// Round 7
// baseline (271.420 us; speedup 1.0000x reference)
//
#include <hip/hip_runtime.h>
#include <hip/hip_bf16.h>

// ---- problem constants ----
#define B_SZ 4
#define S_SZ 2048
#define DM   1024
#define NH   8
#define DK   128
#define DC   32
#define DHR  32
#define DQK  160            // DK + DHR
#define T_TOK (B_SZ * S_SZ) // 8192
#define SCALE 0.07905694150420949f // 1/sqrt(160)
#define C2LOG 0.11405506439f       // SCALE * log2(e): softmax in exp2 domain
#define NT    (S_SZ / 64)   // 32 key tiles
#define NCOL  3328          // concat cols: UQ 1024 | QR 256 | UK 1024 | UV 1024

typedef unsigned int uint;
typedef unsigned short ushort;
typedef __attribute__((ext_vector_type(8))) short short8;
typedef __attribute__((ext_vector_type(4))) float floatx4;
typedef __attribute__((ext_vector_type(16))) float floatx16;
typedef __attribute__((ext_vector_type(4))) uint uintx4;

__device__ __forceinline__ ushort f2bf(float f) {
    uint u = __float_as_uint(f);
    uint r = u + 0x7fffu + ((u >> 16) & 1u);
    return (ushort)(r >> 16);
}
__device__ __forceinline__ uint packbf(float x, float y) {
    return (uint)f2bf(x) | ((uint)f2bf(y) << 16);
}

// async global->LDS, 16B per lane; lds dest = wave-uniform base + lane*16
__device__ __forceinline__ void glds16(const ushort* g, ushort* l) {
    __builtin_amdgcn_global_load_lds(
        (const __attribute__((address_space(1))) uint*)g,
        (__attribute__((address_space(3))) uint*)l, 16, 0, 0);
}

// ============================================================
// Kernel P: merged prep (unchanged from round 6)
// ============================================================
__global__ __launch_bounds__(256) void prep_kernel(
    const float* __restrict__ W_O,
    const float* __restrict__ W_UQ, const float* __restrict__ b_UQ,
    const float* __restrict__ W_QR, const float* __restrict__ b_QR,
    const float* __restrict__ W_UK, const float* __restrict__ b_UK,
    const float* __restrict__ W_UV, const float* __restrict__ b_UV,
    const float* __restrict__ W_DQ, const float* __restrict__ b_DQ,
    const float* __restrict__ W_DKV, const float* __restrict__ b_DKV,
    const float* __restrict__ W_KR, const float* __restrict__ b_KR,
    ushort* __restrict__ wot,
    ushort* __restrict__ wcat, float* __restrict__ bcat,
    ushort* __restrict__ wdcat, float* __restrict__ bdcat)
{
    __shared__ float t[32][33];
    const int bid = blockIdx.x;
    const int tx = threadIdx.x & 31, ty = threadIdx.x >> 5;

    if (bid < 1024) {
        const int n0 = (bid & 31) * 32, k0 = (bid >> 5) * 32;
        #pragma unroll
        for (int j = 0; j < 32; j += 8)
            t[ty + j][tx] = W_O[(size_t)(k0 + ty + j) * DM + n0 + tx];
        __syncthreads();
        #pragma unroll
        for (int j = 0; j < 32; j += 8)
            wot[(size_t)(n0 + ty + j) * DM + k0 + tx] = f2bf(t[tx][ty + j]);
    } else if (bid < 1128) {
        const int c0 = (bid - 1024) * 32;
        const float* W; const float* bias; int stride, sc0;
        if (c0 < 1024)      { W = W_UQ; bias = b_UQ; stride = 1024; sc0 = c0; }
        else if (c0 < 1280) { W = W_QR; bias = b_QR; stride = 256;  sc0 = c0 - 1024; }
        else if (c0 < 2304) { W = W_UK; bias = b_UK; stride = 1024; sc0 = c0 - 1280; }
        else                { W = W_UV; bias = b_UV; stride = 1024; sc0 = c0 - 2304; }
        #pragma unroll
        for (int j = 0; j < 4; ++j) {
            int k = ty + j * 8;
            t[k][tx] = W[(size_t)k * stride + sc0 + tx];
        }
        __syncthreads();
        #pragma unroll
        for (int j = 0; j < 4; ++j) {
            int cc = ty + j * 8;
            wcat[(size_t)(c0 + cc) * 32 + tx] = f2bf(t[tx][cc]);
        }
        if (threadIdx.x < 32) bcat[c0 + threadIdx.x] = bias[sc0 + threadIdx.x];
    } else {
        const int idx = bid - 1128;
        const int wsel = idx >> 5;          // 0..2
        const int k0 = (idx & 31) * 32;
        const float* W    = (wsel == 0) ? W_DQ  : (wsel == 1) ? W_DKV : W_KR;
        const float* bias = (wsel == 0) ? b_DQ  : (wsel == 1) ? b_DKV : b_KR;
        #pragma unroll
        for (int j = 0; j < 32; j += 8)
            t[ty + j][tx] = W[(size_t)(k0 + ty + j) * 32 + tx];
        __syncthreads();
        #pragma unroll
        for (int j = 0; j < 32; j += 8)
            wdcat[(size_t)(wsel * 32 + ty + j) * DM + k0 + tx] = f2bf(t[tx][ty + j]);
        if (k0 == 0 && threadIdx.x < 32)
            bdcat[wsel * 32 + threadIdx.x] = bias[threadIdx.x];
    }
}

// ============================================================
// Kernel 1 (round-7): latent projections via MFMA, h_t staged
// through LDS with coalesced glds16 (fixes round-6's 16B/4KB-row
// gather: one load touched 64 lines using 16B each = 4x overfetch).
// Block = 16 tokens, 128 thr (2 waves; wave w owns cols w*48..+47).
// h_t chunks of [16 tok][128 k] fp32 = 8 KB, double-buffered,
// single barrier per chunk (R4 pattern). Rows are 512B so the XOR
// swizzle x=((d>>9)&7)<<4 preserves rows exactly: inverse-source on
// the DMA, XOR on ds_read_b128 (uniform 8-slot spread, conflict-free).
// ============================================================
__global__ __launch_bounds__(128) void latent_mfma_kernel(
    const float* __restrict__ h_t,
    const ushort* __restrict__ wdcat, const float* __restrict__ bdcat,
    ushort* __restrict__ cqbf, ushort* __restrict__ ckvbf, ushort* __restrict__ krbf)
{
    __shared__ __align__(16) float hsl[2 * 2048]; // 2 x 8192 B
    const int tid  = threadIdx.x;
    const int wave = tid >> 6;          // 0..1
    const int lane = tid & 63;
    const int quad = lane >> 4;
    const int l16  = lane & 15;
    const int t0 = blockIdx.x * 16;

    // staging: dest byte d -> global byte (row*4096 + swizzled col)
    int soff[4], ldst[4];
    #pragma unroll
    for (int j = 0; j < 4; ++j) {
        int d = (tid + j * 128) * 16;
        int la = d ^ (((d >> 9) & 7) << 4);   // row (bits 9..) preserved
        soff[j] = (d >> 9) * 4096 + (la & 511);
        ldst[j] = (wave * 64 + j * 128) * 16; // wave-uniform; HW adds lane*16
    }
    const char* hbase = (const char*)(h_t + (size_t)t0 * DM);

    // prologue: chunk 0 -> buf 0
    #pragma unroll
    for (int j = 0; j < 4; ++j)
        glds16((const ushort*)(hbase + soff[j]), (ushort*)((char*)hsl + ldst[j]));

    floatx4 acc[3];
    #pragma unroll
    for (int ct = 0; ct < 3; ++ct) acc[ct] = (floatx4){0.f, 0.f, 0.f, 0.f};

    const int xorm = (l16 & 7) << 4;

    for (int c = 0; c < 8; ++c) {
        const int cur = c & 1, nxt = cur ^ 1;
        __syncthreads(); // drains prev glds; buf[cur] ready
        if (c + 1 < 8) {
            #pragma unroll
            for (int j = 0; j < 4; ++j)
                glds16((const ushort*)(hbase + (c + 1) * 512 + soff[j]),
                       (ushort*)((char*)hsl + nxt * 8192 + ldst[j]));
        }
        const char* hb = (const char*)hsl + cur * 8192;
        #pragma unroll
        for (int st = 0; st < 4; ++st) {
            const int la0 = l16 * 512 + st * 128 + quad * 32;
            float4 f0 = *(const float4*)(hb + (la0 ^ xorm));
            float4 f1 = *(const float4*)(hb + ((la0 + 16) ^ xorm));
            uint b0, b1, b2, b3;
            asm("v_cvt_pk_bf16_f32 %0, %1, %2" : "=v"(b0) : "v"(f0.x), "v"(f0.y));
            asm("v_cvt_pk_bf16_f32 %0, %1, %2" : "=v"(b1) : "v"(f0.z), "v"(f0.w));
            asm("v_cvt_pk_bf16_f32 %0, %1, %2" : "=v"(b2) : "v"(f1.x), "v"(f1.y));
            asm("v_cvt_pk_bf16_f32 %0, %1, %2" : "=v"(b3) : "v"(f1.z), "v"(f1.w));
            short8 bfr = __builtin_bit_cast(short8, (uintx4){b0, b1, b2, b3});
            #pragma unroll
            for (int ct = 0; ct < 3; ++ct) {
                const int wct = wave * 3 + ct;
                short8 af = *(const short8*)&wdcat[(size_t)(wct * 16 + l16) * DM
                                                   + c * 128 + st * 32 + quad * 8];
                acc[ct] = __builtin_amdgcn_mfma_f32_16x16x32_bf16(af, bfr, acc[ct], 0, 0, 0);
            }
        }
    }

    const int q4 = quad * 4;
    const int tok = t0 + l16;
    #pragma unroll
    for (int ct = 0; ct < 3; ++ct) {
        const int col = (wave * 3 + ct) * 16 + q4;
        float4 b4 = *(const float4*)&bdcat[col];
        uint w0, w1;
        asm("v_cvt_pk_bf16_f32 %0, %1, %2" : "=v"(w0)
            : "v"(acc[ct][0] + b4.x), "v"(acc[ct][1] + b4.y));
        asm("v_cvt_pk_bf16_f32 %0, %1, %2" : "=v"(w1)
            : "v"(acc[ct][2] + b4.z), "v"(acc[ct][3] + b4.w));
        ushort* outp = (col < 32) ? cqbf : (col < 64) ? ckvbf : krbf;
        *(uint2*)&outp[(size_t)tok * 32 + (col & 31)] = make_uint2(w0, w1);
    }
}

// ============================================================
// Kernel 2b: build q/k/v via MFMA (unchanged from round 5)
// ============================================================
__global__ __launch_bounds__(256) void build_qkv_mfma_kernel(
    const ushort* __restrict__ cqbf, const ushort* __restrict__ ckvbf,
    const ushort* __restrict__ krbf,
    const ushort* __restrict__ wcat, const float* __restrict__ bcat,
    ushort* __restrict__ q_ws, ushort* __restrict__ k_ws, ushort* __restrict__ v_ws)
{
    const int tid  = threadIdx.x;
    const int wave = tid >> 6;
    const int lane = tid & 63;
    const int quad = lane >> 4;
    const int l16  = lane & 15;

    const int tok = blockIdx.x * 64 + wave * 16 + l16;
    const int hp  = blockIdx.y;           // head pair 0..3
    const int bb  = tok >> 11, s = tok & 2047;

    const short8 bq  = *(const short8*)&cqbf[tok * 32 + quad * 8];
    const short8 bkv = *(const short8*)&ckvbf[tok * 32 + quad * 8];
    const uint4  kr  = *(const uint4*)&((const uint*)krbf)[tok * 16 + quad * 4];

    const int q4 = quad * 4;

    auto emit = [&](int wrow, ushort* outp, int dbase, short8 bfrag) {
        short8 af = *(const short8*)&wcat[(size_t)(wrow + l16) * 32 + quad * 8];
        floatx4 d = __builtin_amdgcn_mfma_f32_16x16x32_bf16(
            af, bfrag, (floatx4){0.f, 0.f, 0.f, 0.f}, 0, 0, 0);
        float4 b4 = *(const float4*)&bcat[wrow + q4];
        uint w0, w1;
        asm("v_cvt_pk_bf16_f32 %0, %1, %2" : "=v"(w0)
            : "v"(d[0] + b4.x), "v"(d[1] + b4.y));
        asm("v_cvt_pk_bf16_f32 %0, %1, %2" : "=v"(w1)
            : "v"(d[2] + b4.z), "v"(d[3] + b4.w));
        *(uint2*)&outp[dbase + q4] = make_uint2(w0, w1);
    };

    #pragma unroll
    for (int hh = 0; hh < 2; ++hh) {
        const int h = hp * 2 + hh;
        ushort* qp = q_ws + ((size_t)(bb * NH + h) * S_SZ + s) * DQK;
        ushort* kp = k_ws + ((size_t)(bb * NH + h) * S_SZ + s) * DQK;
        ushort* vp = v_ws + ((size_t)(bb * NH + h) * S_SZ + s) * DK;

        #pragma unroll
        for (int seg = 0; seg < 8; ++seg) emit(h * 128 + seg * 16, qp, seg * 16, bq);
        #pragma unroll
        for (int seg = 0; seg < 2; ++seg) emit(1024 + h * 32 + seg * 16, qp, 128 + seg * 16, bq);
        #pragma unroll
        for (int seg = 0; seg < 8; ++seg) emit(1280 + h * 128 + seg * 16, kp, seg * 16, bkv);
        #pragma unroll
        for (int seg = 0; seg < 8; ++seg) emit(2304 + h * 128 + seg * 16, vp, seg * 16, bkv);

        *(uint4*)&kp[128 + quad * 8] = kr;
    }
}

// ============================================================
// Kernel 3: 32x32x16-MFMA flash attention (unchanged from round 4)
// ============================================================
__global__ __launch_bounds__(256, 2) void attn_mfma_kernel(
    const ushort* __restrict__ q_ws, const ushort* __restrict__ k_ws,
    const ushort* __restrict__ v_ws, ushort* __restrict__ o_ws)
{
    __shared__ __align__(16) ushort SH[38912]; // 77824 B
    const int tid  = threadIdx.x;
    const int wave = tid >> 6;   // 0..3
    const int lane = tid & 63;
    const int l32  = lane & 31;
    const int hi   = lane >> 5;
    const int hi8  = hi * 8;

    const int wg = blockIdx.x;
    const int virt = (wg & 7) * 64 + (wg >> 3);
    const int bh = virt >> 4;
    const int b = bh >> 3, h = bh & 7;
    const int s0 = (virt & 15) * 128;
    const int qrow_base = s0 + wave * 32;

    const ushort* kbase = k_ws + (size_t)bh * S_SZ * DQK;
    const ushort* vbase = v_ws + (size_t)bh * S_SZ * DK;

    int ksrc[5];
    #pragma unroll
    for (int j = 0; j < 5; ++j) {
        int d = (tid + j * 256) * 16;
        int r0 = d / 320;
        int la = d;
        #pragma unroll
        for (int dr = -1; dr <= 1; ++dr) {
            int r = r0 + dr;
            int cand = d ^ ((r & 7) << 4);
            if (cand / 320 == r) la = cand;
        }
        ksrc[j] = la;
    }
    const int kdst_us = (wave * 64) * 8;

    short8 qf[10];
    {
        const ushort* qp = q_ws + ((size_t)bh * S_SZ + qrow_base + l32) * DQK + hi8;
        #pragma unroll
        for (int st = 0; st < 10; ++st)
            qf[st] = *(const short8*)&qp[st * 16];
    }

    floatx16 oa[4];
    #pragma unroll
    for (int vt = 0; vt < 4; ++vt)
        oa[vt] = (floatx16){0.f,0.f,0.f,0.f,0.f,0.f,0.f,0.f,
                            0.f,0.f,0.f,0.f,0.f,0.f,0.f,0.f};

    float m2 = -3.0e38f;
    float l_run = 0.f;

    {
        #pragma unroll
        for (int j = 0; j < 5; ++j)
            glds16((const ushort*)((const char*)kbase + ksrc[j]),
                   SH + kdst_us + j * 2048);
        uint vpa[8], vpb[8];
        const uint* vg = (const uint*)vbase;
        #pragma unroll
        for (int c = 0; c < 8; ++c) {
            int kp = wave * 8 + c;
            vpa[c] = vg[(2 * kp) * 64 + lane];
            vpb[c] = vg[(2 * kp + 1) * 64 + lane];
        }
        uint* vt32 = (uint*)(SH + 20480);
        uint lo[8], hh[8];
        #pragma unroll
        for (int c = 0; c < 8; ++c) {
            lo[c] = (vpa[c] & 0xffffu) | (vpb[c] << 16);
            hh[c] = (vpa[c] >> 16) | (vpb[c] & 0xffff0000u);
        }
        *(uint4*)&vt32[(2 * lane) * 36 + wave * 8]     = make_uint4(lo[0], lo[1], lo[4], lo[5]);
        *(uint4*)&vt32[(2 * lane) * 36 + wave * 8 + 4] = make_uint4(lo[2], lo[3], lo[6], lo[7]);
        *(uint4*)&vt32[(2 * lane + 1) * 36 + wave * 8]     = make_uint4(hh[0], hh[1], hh[4], hh[5]);
        *(uint4*)&vt32[(2 * lane + 1) * 36 + wave * 8 + 4] = make_uint4(hh[2], hh[3], hh[6], hh[7]);
    }

    const int kmask = (l32 & 7) << 4;

    for (int kt = 0; kt < NT; ++kt) {
        const int cur = kt & 1, nxt = cur ^ 1;
        __syncthreads();

        uint vpa[8], vpb[8];
        if (kt + 1 < NT) {
            const char* kg = (const char*)(kbase + (size_t)(kt + 1) * 64 * DQK);
            #pragma unroll
            for (int j = 0; j < 5; ++j)
                glds16((const ushort*)(kg + ksrc[j]),
                       SH + nxt * 10240 + kdst_us + j * 2048);
            const uint* vg = (const uint*)(vbase + (size_t)(kt + 1) * 64 * DK);
            #pragma unroll
            for (int c = 0; c < 8; ++c) {
                int kp = wave * 8 + c;
                vpa[c] = vg[(2 * kp) * 64 + lane];
                vpb[c] = vg[(2 * kp + 1) * 64 + lane];
            }
        }

        const char* kbufc = (const char*)(SH + cur * 10240);
        floatx16 sc[2];
        __builtin_amdgcn_s_setprio(1);
        #pragma unroll
        for (int kb = 0; kb < 2; ++kb) {
            floatx16 acc = (floatx16){0.f,0.f,0.f,0.f,0.f,0.f,0.f,0.f,
                                      0.f,0.f,0.f,0.f,0.f,0.f,0.f,0.f};
            const int row_la = (kb * 32 + l32) * 320 + hi * 16;
            #pragma unroll
            for (int st = 0; st < 10; ++st) {
                short8 kf = *(const short8*)(kbufc + ((row_la + st * 32) ^ kmask));
                acc = __builtin_amdgcn_mfma_f32_32x32x16_bf16(kf, qf[st], acc, 0, 0, 0);
            }
            sc[kb] = acc;
        }
        __builtin_amdgcn_s_setprio(0);

        {
            float tmax = -3.0e38f;
            #pragma unroll
            for (int kb = 0; kb < 2; ++kb)
                #pragma unroll
                for (int r = 0; r < 16; ++r)
                    tmax = fmaxf(tmax, sc[kb][r]);
            tmax *= C2LOG;
            tmax = fmaxf(tmax, __shfl_xor(tmax, 32));

            if (__any(tmax > m2 + 8.0f)) {
                float mnew = fmaxf(m2, tmax);
                float al = __builtin_amdgcn_exp2f(m2 - mnew);
                m2 = mnew;
                l_run *= al;
                #pragma unroll
                for (int vt = 0; vt < 4; ++vt)
                    #pragma unroll
                    for (int r = 0; r < 16; ++r)
                        oa[vt][r] *= al;
            }

            float rsum = 0.f;
            #pragma unroll
            for (int kb = 0; kb < 2; ++kb)
                #pragma unroll
                for (int r = 0; r < 16; ++r) {
                    float p = __builtin_amdgcn_exp2f(__builtin_fmaf(sc[kb][r], C2LOG, -m2));
                    sc[kb][r] = p;
                    rsum += p;
                }
            rsum += __shfl_xor(rsum, 32);
            l_run += rsum;
        }

        const ushort* vtc = SH + 20480 + cur * 9216;
        __builtin_amdgcn_s_setprio(1);
        #pragma unroll
        for (int kb = 0; kb < 2; ++kb) {
            #pragma unroll
            for (int s = 0; s < 2; ++s) {
                uint w0, w1, w2, w3;
                asm("v_cvt_pk_bf16_f32 %0, %1, %2" : "=v"(w0)
                    : "v"(sc[kb][8 * s + 0]), "v"(sc[kb][8 * s + 1]));
                asm("v_cvt_pk_bf16_f32 %0, %1, %2" : "=v"(w1)
                    : "v"(sc[kb][8 * s + 2]), "v"(sc[kb][8 * s + 3]));
                asm("v_cvt_pk_bf16_f32 %0, %1, %2" : "=v"(w2)
                    : "v"(sc[kb][8 * s + 4]), "v"(sc[kb][8 * s + 5]));
                asm("v_cvt_pk_bf16_f32 %0, %1, %2" : "=v"(w3)
                    : "v"(sc[kb][8 * s + 6]), "v"(sc[kb][8 * s + 7]));
                short8 pv = __builtin_bit_cast(short8, (uintx4){w0, w1, w2, w3});
                #pragma unroll
                for (int vt = 0; vt < 4; ++vt) {
                    short8 vf = *(const short8*)&vtc[(size_t)(vt * 32 + l32) * 72
                                                     + kb * 32 + s * 16 + hi8];
                    oa[vt] = __builtin_amdgcn_mfma_f32_32x32x16_bf16(vf, pv, oa[vt], 0, 0, 0);
                }
            }
        }
        __builtin_amdgcn_s_setprio(0);

        if (kt + 1 < NT) {
            uint* vt32 = (uint*)(SH + 20480 + nxt * 9216);
            uint lo[8], hh[8];
            #pragma unroll
            for (int c = 0; c < 8; ++c) {
                lo[c] = (vpa[c] & 0xffffu) | (vpb[c] << 16);
                hh[c] = (vpa[c] >> 16) | (vpb[c] & 0xffff0000u);
            }
            *(uint4*)&vt32[(2 * lane) * 36 + wave * 8]     = make_uint4(lo[0], lo[1], lo[4], lo[5]);
            *(uint4*)&vt32[(2 * lane) * 36 + wave * 8 + 4] = make_uint4(lo[2], lo[3], lo[6], lo[7]);
            *(uint4*)&vt32[(2 * lane + 1) * 36 + wave * 8]     = make_uint4(hh[0], hh[1], hh[4], hh[5]);
            *(uint4*)&vt32[(2 * lane + 1) * 36 + wave * 8 + 4] = make_uint4(hh[2], hh[3], hh[6], hh[7]);
        }
    }

    __syncthreads();
    ushort* ot = SH + wave * (32 * 136);
    uint* ot32 = (uint*)ot;
    {
        float inv = 1.0f / l_run;
        #pragma unroll
        for (int vt = 0; vt < 4; ++vt)
            #pragma unroll
            for (int g = 0; g < 4; ++g) {
                int base = l32 * 68 + vt * 16 + g * 4 + hi * 2;
                ot32[base]     = packbf(oa[vt][g * 4 + 0] * inv, oa[vt][g * 4 + 1] * inv);
                ot32[base + 1] = packbf(oa[vt][g * 4 + 2] * inv, oa[vt][g * 4 + 3] * inv);
            }
    }
    #pragma unroll
    for (int pass = 0; pass < 8; ++pass) {
        int row_in = pass * 4 + (lane >> 4);
        int col8 = (lane & 15) * 8;
        uint4 v = *(const uint4*)&ot[row_in * 136 + col8];
        int srow = qrow_base + row_in;
        *(uint4*)(o_ws + (((size_t)b * S_SZ + srow) * NH + h) * DK + col8) = v;
    }
}

// ============================================================
// Kernel 4b (round-7): out = o_ws @ W_O + b_O via MFMA.
// BK=64 (16 k-iters, half the barriers of BK=32), LDS 32 KB.
// 128B LDS rows would be a 16-way conflict -> row-preserving XOR
// swizzle x=((d>>7)&7)<<4: inverse-source on glds16, XOR on reads.
// XCD-aware 1D grid: each XCD owns an m-stripe (A 2MB + B 2MB L2-fit).
// ============================================================
__global__ __launch_bounds__(256) void out_gemm_mfma_kernel(
    const ushort* __restrict__ A,    // o_ws [8192][1024] bf16
    const ushort* __restrict__ BT,   // wot  [1024 n][1024 k] bf16
    const float* __restrict__ b_O, float* __restrict__ out)
{
    __shared__ __align__(16) ushort As[128 * 64];
    __shared__ __align__(16) ushort Bs[128 * 64];

    const int tid = threadIdx.x;
    const int wave = tid >> 6;
    const int lane = tid & 63;
    const int quad = lane >> 4;
    const int l16 = lane & 15;
    const int wr = wave >> 1, wc = wave & 1;

    const int wg = blockIdx.x;                 // 512 blocks
    const int virt = (wg & 7) * 64 + (wg >> 3);
    const int n0 = (virt & 7) * 128;
    const int m0 = (virt >> 3) * 128;

    int soff[4], ldst[4];
    #pragma unroll
    for (int j = 0; j < 4; ++j) {
        int d = (tid + j * 256) * 16;              // dest byte in [0,16384)
        int la = d ^ (((d >> 7) & 7) << 4);        // row (bits 7..) preserved
        soff[j] = (d >> 7) * 2048 + (la & 127);    // row*DM*2 + swz col
        ldst[j] = (wave * 64 + j * 256) * 16;      // wave-uniform dest base
    }

    floatx4 acc[4][4];
    #pragma unroll
    for (int mt = 0; mt < 4; ++mt)
        #pragma unroll
        for (int nt = 0; nt < 4; ++nt)
            acc[mt][nt] = (floatx4){0.f, 0.f, 0.f, 0.f};

    const int xorm = (l16 & 7) << 4;

    for (int k0 = 0; k0 < DM; k0 += 64) {
        __syncthreads();
        #pragma unroll
        for (int j = 0; j < 4; ++j) {
            glds16((const ushort*)((const char*)A + (size_t)m0 * 2048 + k0 * 2 + soff[j]),
                   (ushort*)((char*)As + ldst[j]));
            glds16((const ushort*)((const char*)BT + (size_t)n0 * 2048 + k0 * 2 + soff[j]),
                   (ushort*)((char*)Bs + ldst[j]));
        }
        __syncthreads();

        short8 af[4][2], bf[4][2];
        #pragma unroll
        for (int mt = 0; mt < 4; ++mt)
            #pragma unroll
            for (int hh = 0; hh < 2; ++hh) {
                int la_a = (wr * 64 + mt * 16 + l16) * 128 + hh * 64 + quad * 16;
                af[mt][hh] = *(const short8*)((const char*)As + (la_a ^ xorm));
                int la_b = (wc * 64 + mt * 16 + l16) * 128 + hh * 64 + quad * 16;
                bf[mt][hh] = *(const short8*)((const char*)Bs + (la_b ^ xorm));
            }
        #pragma unroll
        for (int mt = 0; mt < 4; ++mt)
            #pragma unroll
            for (int nt = 0; nt < 4; ++nt) {
                acc[mt][nt] = __builtin_amdgcn_mfma_f32_16x16x32_bf16(af[mt][0], bf[nt][0], acc[mt][nt], 0, 0, 0);
                acc[mt][nt] = __builtin_amdgcn_mfma_f32_16x16x32_bf16(af[mt][1], bf[nt][1], acc[mt][nt], 0, 0, 0);
            }
    }

    float bo[4];
    #pragma unroll
    for (int nt = 0; nt < 4; ++nt) bo[nt] = b_O[n0 + wc * 64 + nt * 16 + l16];

    #pragma unroll
    for (int mt = 0; mt < 4; ++mt) {
        #pragma unroll
        for (int r = 0; r < 4; ++r) {
            int row = m0 + wr * 64 + mt * 16 + quad * 4 + r;
            float* orow = out + (size_t)row * DM + n0 + wc * 64;
            #pragma unroll
            for (int nt = 0; nt < 4; ++nt)
                orow[nt * 16 + l16] = acc[mt][nt][r] + bo[nt];
        }
    }
}

// ============================================================
extern "C" void kernel_launch(void* const* d_in, const int* in_sizes, int n_in,
                              void* d_out, int out_size, void* d_ws, size_t ws_size,
                              hipStream_t stream) {
    (void)in_sizes; (void)n_in; (void)out_size; (void)ws_size;

    const float* h_t   = (const float*)d_in[0];
    const float* W_DQ  = (const float*)d_in[1];
    const float* b_DQ  = (const float*)d_in[2];
    const float* W_UQ  = (const float*)d_in[3];
    const float* b_UQ  = (const float*)d_in[4];
    const float* W_DKV = (const float*)d_in[5];
    const float* b_DKV = (const float*)d_in[6];
    const float* W_UK  = (const float*)d_in[7];
    const float* b_UK  = (const float*)d_in[8];
    const float* W_UV  = (const float*)d_in[9];
    const float* b_UV  = (const float*)d_in[10];
    const float* W_QR  = (const float*)d_in[11];
    const float* b_QR  = (const float*)d_in[12];
    const float* W_KR  = (const float*)d_in[13];
    const float* b_KR  = (const float*)d_in[14];
    const float* W_O   = (const float*)d_in[15];
    const float* b_O   = (const float*)d_in[16];

    ushort* cqbf  = (ushort*)d_ws;                      // [8192][32]
    ushort* ckvbf = cqbf + (size_t)T_TOK * DC;
    ushort* krbf  = ckvbf + (size_t)T_TOK * DC;
    ushort* wcat  = krbf + (size_t)T_TOK * DC;          // [3328][32]
    float*  bcat  = (float*)(wcat + (size_t)NCOL * DC); // [3328]
    ushort* wdcat = (ushort*)(bcat + NCOL);             // [96][1024]
    float*  bdcat = (float*)(wdcat + (size_t)96 * DM);  // [96]
    ushort* q_ws  = (ushort*)(bdcat + 96);
    ushort* k_ws  = q_ws + (size_t)B_SZ * NH * S_SZ * DQK;
    ushort* v_ws  = k_ws + (size_t)B_SZ * NH * S_SZ * DQK;
    ushort* o_ws  = v_ws + (size_t)B_SZ * NH * S_SZ * DK;
    ushort* wot   = o_ws + (size_t)T_TOK * DM;

    float* out = (float*)d_out;

    prep_kernel<<<1224, 256, 0, stream>>>(
        W_O, W_UQ, b_UQ, W_QR, b_QR, W_UK, b_UK, W_UV, b_UV,
        W_DQ, b_DQ, W_DKV, b_DKV, W_KR, b_KR,
        wot, wcat, bcat, wdcat, bdcat);

    latent_mfma_kernel<<<T_TOK / 16, 128, 0, stream>>>(
        h_t, wdcat, bdcat, cqbf, ckvbf, krbf);

    build_qkv_mfma_kernel<<<dim3(T_TOK / 64, 4), 256, 0, stream>>>(
        cqbf, ckvbf, krbf, wcat, bcat, q_ws, k_ws, v_ws);

    attn_mfma_kernel<<<512, 256, 0, stream>>>(
        q_ws, k_ws, v_ws, o_ws);

    out_gemm_mfma_kernel<<<512, 256, 0, stream>>>(
        o_ws, wot, b_O, out);
}